// Round 15
// baseline (84.885 us; speedup 1.0000x reference)
//
#include <hip/hip_runtime.h>

#define FDIM   251
#define NFILT  80
#define KPAD   256        // K padded to 8 chunks of 32 (zeros past 250)
#define T_IN   64000
#define T_OUT  63750      // 64000 - 251 + 1
#define NCHUNK 1024       // output positions per block; wave owns contiguous 256
#define NFT    5          // filter tiles (16 filters each)
#define CPYLEN 648        // dwords per shifted copy; 648 % 32 == 8 -> bank stagger
#define XSTOT  (8 * CPYLEN)

typedef short bf16x8 __attribute__((ext_vector_type(8)));
typedef float f32x4  __attribute__((ext_vector_type(4)));

__device__ __forceinline__ unsigned short f2bf(float f) {
  unsigned int u = __float_as_uint(f);
  unsigned int r = (u + 0x7fffu + ((u >> 16) & 1u)) >> 16;   // RNE
  return (unsigned short)r;
}
__device__ __forceinline__ unsigned int packbf(float a, float b) {
  return (unsigned int)f2bf(a) | ((unsigned int)f2bf(b) << 16);
}

// ---------------------------------------------------------------------------
// Filter construction (validated rounds 1-14). Emits bf16 W[80][256].
// ---------------------------------------------------------------------------
__device__ __forceinline__ void norm_pm1_shared(float* a, float* scratch, int tid) {
  float v  = (tid < FDIM) ? a[tid] : 0.f;
  float mn = (tid < FDIM) ? v : 1e30f;
  float mx = (tid < FDIM) ? v : -1e30f;
  #pragma unroll
  for (int o = 32; o > 0; o >>= 1) {
    mn = fminf(mn, __shfl_down(mn, o));
    mx = fmaxf(mx, __shfl_down(mx, o));
  }
  const int wid = tid >> 6;
  if ((tid & 63) == 0) { scratch[wid] = mn; scratch[4 + wid] = mx; }
  __syncthreads();
  if (tid == 0) {
    scratch[0] = fminf(fminf(scratch[0], scratch[1]), fminf(scratch[2], scratch[3]));
    scratch[4] = fmaxf(fmaxf(scratch[4], scratch[5]), fmaxf(scratch[6], scratch[7]));
  }
  __syncthreads();
  const float gmn = scratch[0], gmx = scratch[4];
  const float nv = 2.f * (v - gmn) / (gmx - gmn + 1e-6f) - 1.f;
  __syncthreads();
  float s = (tid < FDIM) ? nv : 0.f;
  #pragma unroll
  for (int o = 32; o > 0; o >>= 1) s += __shfl_down(s, o);
  if ((tid & 63) == 0) scratch[wid] = s;
  __syncthreads();
  if (tid == 0) scratch[0] = (scratch[0] + scratch[1] + scratch[2] + scratch[3]) / 251.f;
  __syncthreads();
  const float mean = scratch[0];
  if (tid < FDIM) a[tid] = nv - mean;
  __syncthreads();
}

__global__ __launch_bounds__(256) void build_filters_kernel(
    const float* __restrict__ nf1, const float* __restrict__ nf2,
    const float* __restrict__ nf3, const float* __restrict__ nf4,
    const float* __restrict__ amp1, const float* __restrict__ amp2,
    unsigned short* __restrict__ Wbf) {
  __shared__ float ir1[FDIM], ir2[FDIM], casc[FDIM];
  __shared__ float scratch[8];
  const int f = blockIdx.x, tid = threadIdx.x;
  const float FS  = 16000.f;
  const float MF  = 50.f / 16000.f;
  const float PIF = 3.14159265358979323846f;
  const float TPI = 6.28318530717958647692f;

  const float f1 = fminf(fmaxf(fabsf(nf1[f]) + MF, 0.f), 0.5f);
  const float f2 = fminf(fmaxf(f1 + fabsf(nf2[f] - f1) + MF, 0.f), 0.5f);
  const float f3 = fminf(fmaxf(fabsf(nf3[f]) + MF, 0.f), 0.5f);
  const float f4 = fminf(fmaxf(f3 + fabsf(nf4[f] - f3) + MF, 0.f), 0.5f);
  const float a1 = fabsf(amp1[f]);
  const float a2 = fabsf(amp2[f]);

  if (tid < FDIM) {
    const float t = (float)(tid + 1) / FS;
    {
      const float fcs = 0.5f * (f1 + f2) * FS, bws = (f2 - f1) * FS;
      const float pb = PIF * bws;
      ir1[tid] = a1 * expf(-2.f * pb * pb * (t * t)) * cosf(TPI * fcs * t);
    }
    {
      const float fcs = 0.5f * (f3 + f4) * FS, bws = (f4 - f3) * FS;
      const float pb = PIF * bws;
      ir2[tid] = a2 * expf(-2.f * pb * pb * (t * t)) * cosf(TPI * fcs * t);
    }
  }
  __syncthreads();
  norm_pm1_shared(ir1, scratch, tid);
  norm_pm1_shared(ir2, scratch, tid);

  if (tid < FDIM) {
    const int i = tid;
    const int plo = (i - 125 > 0) ? (i - 125) : 0;
    const int phi = (i + 125 < 250) ? (i + 125) : 250;
    float s = 0.f;
    for (int p = plo; p <= phi; ++p) s += ir1[p] * ir2[p + 125 - i];
    casc[i] = s;
  }
  __syncthreads();
  norm_pm1_shared(casc, scratch, tid);

  if (tid < KPAD) {
    float v = 0.f;
    if (tid < FDIM) {
      const float win = 0.54f - 0.46f * cosf(TPI * ((float)tid / 250.f));
      v = casc[tid] * win;
    }
    Wbf[(size_t)f * KPAD + tid] = f2bf(v);
  }
}

// ---------------------------------------------------------------------------
// Implicit-GEMM conv: EXACT round-7 kernel + runtime store mask.
//   smask = 1: identical to r7 (correct output, 59.7 us total measured).
//   smask = 0: same instruction stream, all staging/LDS/MFMA executed,
//              ZERO global stores (runtime-false predicate; the opaque
//              kernel arg prevents DCE of the compute).
// Launching both partitions the kernel: dur_us - 59.7 = T_nostore, the
// pure compute-side time. This decides between the "compute ~21us +
// unoverlapped 28us HBM drain" model (dur ~80) and "issue-bound,
// stores nearly free" (dur ~105+).
// ---------------------------------------------------------------------------
__global__ __launch_bounds__(256, 4) void conv_mfma_kernel(
    const float* __restrict__ xin, const unsigned short* __restrict__ Wbf,
    float* __restrict__ outp, int smask) {
  __shared__ __align__(16) unsigned int xs[XSTOT];
  const int tid = threadIdx.x;
  const int n0  = blockIdx.x * NCHUNK;
  const int ft  = blockIdx.y;
  const int b   = blockIdx.z;
  const int l   = tid & 63, w = tid >> 6;
  const int m   = l & 15, h = l >> 4;

  // ---- stage x as 8 shifted bf16-pair copies: C_j[i] = (x[2i+j], x[2i+j+1]) ----
  const float* xg = xin + (size_t)b * T_IN;
  for (int i = tid; i < CPYLEN - 4; i += 256) {
    float e[10];
    #pragma unroll
    for (int q = 0; q < 10; ++q) {
      const int g = n0 + 2 * i + q;
      e[q] = (g < T_IN) ? xg[g] : 0.f;
    }
    #pragma unroll
    for (int j = 0; j < 8; ++j)
      xs[j * CPYLEN + i] = packbf(e[j], e[j + 1]);
  }

  // ---- W fragments (A-operand): lane row = m -> W[ft*16+m][k=8h+j+32c] ----
  const short* Wp = (const short*)Wbf;
  bf16x8 afr[8];
  #pragma unroll
  for (int c = 0; c < 8; ++c)
    afr[c] = *(const bf16x8*)(Wp + (ft * 16 + m) * KPAD + c * 32 + h * 8);

  __syncthreads();

  // lane-constant B(x) addressing (validated r4-r14):
  // tile at t_loc, chunk c -> copy m&7, 16B-unit index t_loc/8 + lane_q + 4c
  const unsigned int* psrc = xs + (m & 7) * CPYLEN;
  const int lane_q = h + (m >> 3);
  const int tw0 = w * 256;                     // wave's local t base (16 tiles)
  const size_t rowh = ((size_t)b * NFILT + ft * 16 + 4 * h) * T_OUT;
  const int tlim = smask ? T_OUT : -1;         // smask=0 -> no store executes

  for (int jp = 0; jp < 8; ++jp) {             // 8 pairs of 16-t tiles, 2 chains
    const int qA = ((tw0 + jp * 32) >> 3) + lane_q;
    f32x4 accA = (f32x4){0.f, 0.f, 0.f, 0.f};
    f32x4 accB = (f32x4){0.f, 0.f, 0.f, 0.f};

    #pragma unroll
    for (int c = 0; c < 8; ++c) {
      const bf16x8 xa = *(const bf16x8*)(psrc + 4 * (qA + 4 * c));
      const bf16x8 xb = *(const bf16x8*)(psrc + 4 * (qA + 2 + 4 * c));
      accA = __builtin_amdgcn_mfma_f32_16x16x32_bf16(afr[c], xa, accA, 0, 0, 0);
      accB = __builtin_amdgcn_mfma_f32_16x16x32_bf16(afr[c], xb, accB, 0, 0, 0);
    }

    const int tgA = n0 + tw0 + jp * 32 + m;    // D col = m
    const int tgB = tgA + 16;
    #pragma unroll
    for (int r = 0; r < 4; ++r) {              // D row = 4h + r
      const size_t rb = rowh + (size_t)r * T_OUT;
      if (tgA < tlim) outp[rb + tgA] = accA[r];
      if (tgB < tlim) outp[rb + tgB] = accB[r];
    }
  }
}

// ---------------------------------------------------------------------------
extern "C" void kernel_launch(void* const* d_in, const int* in_sizes, int n_in,
                              void* d_out, int out_size, void* d_ws, size_t ws_size,
                              hipStream_t stream) {
  const float* x    = (const float*)d_in[0];
  const float* nf1  = (const float*)d_in[1];
  const float* nf2  = (const float*)d_in[2];
  const float* nf3  = (const float*)d_in[3];
  const float* nf4  = (const float*)d_in[4];
  const float* amp1 = (const float*)d_in[5];
  const float* amp2 = (const float*)d_in[6];
  unsigned short* Wbf = (unsigned short*)d_ws;   // 80*256*2 = 40 KB scratch
  float* out = (float*)d_out;

  build_filters_kernel<<<NFILT, 256, 0, stream>>>(nf1, nf2, nf3, nf4, amp1, amp2, Wbf);

  dim3 grid((T_OUT + NCHUNK - 1) / NCHUNK, NFT, 8);   // 63 x 5 x 8
  // dispatch 1: real kernel (correct output)
  conv_mfma_kernel<<<grid, 256, 0, stream>>>(x, Wbf, out, 1);
  // dispatch 2: ablation probe - identical compute, zero global stores
  conv_mfma_kernel<<<grid, 256, 0, stream>>>(x, Wbf, out, 0);
}

// Round 16
// 69.048 us; speedup vs baseline: 1.2294x; 1.2294x over previous
//
#include <hip/hip_runtime.h>

#define FDIM   251
#define NFILT  80
#define KPAD   256        // K padded to 8 chunks of 32 (zeros past 250)
#define T_IN   64000
#define T_OUT  63750      // 64000 - 251 + 1
#define NCHUNK 512        // output positions per block; wave owns contiguous 128
#define NXB    125        // t-chunks
#define NFT    5          // filter tiles (16 filters each) - looped IN-block
#define CPYLEN 392        // dwords per shifted copy; 392 % 32 == 8 -> bank stagger
#define XSTOT  (8 * CPYLEN)   // 12.25 KB LDS

typedef short bf16x8 __attribute__((ext_vector_type(8)));
typedef float f32x4  __attribute__((ext_vector_type(4)));

__device__ __forceinline__ unsigned short f2bf(float f) {
  unsigned int u = __float_as_uint(f);
  unsigned int r = (u + 0x7fffu + ((u >> 16) & 1u)) >> 16;   // RNE
  return (unsigned short)r;
}
__device__ __forceinline__ unsigned int packbf(float a, float b) {
  return (unsigned int)f2bf(a) | ((unsigned int)f2bf(b) << 16);
}

// ---------------------------------------------------------------------------
// Filter construction (validated rounds 1-15). Emits bf16 W[80][256].
// ---------------------------------------------------------------------------
__device__ __forceinline__ void norm_pm1_shared(float* a, float* scratch, int tid) {
  float v  = (tid < FDIM) ? a[tid] : 0.f;
  float mn = (tid < FDIM) ? v : 1e30f;
  float mx = (tid < FDIM) ? v : -1e30f;
  #pragma unroll
  for (int o = 32; o > 0; o >>= 1) {
    mn = fminf(mn, __shfl_down(mn, o));
    mx = fmaxf(mx, __shfl_down(mx, o));
  }
  const int wid = tid >> 6;
  if ((tid & 63) == 0) { scratch[wid] = mn; scratch[4 + wid] = mx; }
  __syncthreads();
  if (tid == 0) {
    scratch[0] = fminf(fminf(scratch[0], scratch[1]), fminf(scratch[2], scratch[3]));
    scratch[4] = fmaxf(fmaxf(scratch[4], scratch[5]), fmaxf(scratch[6], scratch[7]));
  }
  __syncthreads();
  const float gmn = scratch[0], gmx = scratch[4];
  const float nv = 2.f * (v - gmn) / (gmx - gmn + 1e-6f) - 1.f;
  __syncthreads();
  float s = (tid < FDIM) ? nv : 0.f;
  #pragma unroll
  for (int o = 32; o > 0; o >>= 1) s += __shfl_down(s, o);
  if ((tid & 63) == 0) scratch[wid] = s;
  __syncthreads();
  if (tid == 0) scratch[0] = (scratch[0] + scratch[1] + scratch[2] + scratch[3]) / 251.f;
  __syncthreads();
  const float mean = scratch[0];
  if (tid < FDIM) a[tid] = nv - mean;
  __syncthreads();
}

__global__ __launch_bounds__(256) void build_filters_kernel(
    const float* __restrict__ nf1, const float* __restrict__ nf2,
    const float* __restrict__ nf3, const float* __restrict__ nf4,
    const float* __restrict__ amp1, const float* __restrict__ amp2,
    unsigned short* __restrict__ Wbf) {
  __shared__ float ir1[FDIM], ir2[FDIM], casc[FDIM];
  __shared__ float scratch[8];
  const int f = blockIdx.x, tid = threadIdx.x;
  const float FS  = 16000.f;
  const float MF  = 50.f / 16000.f;
  const float PIF = 3.14159265358979323846f;
  const float TPI = 6.28318530717958647692f;

  const float f1 = fminf(fmaxf(fabsf(nf1[f]) + MF, 0.f), 0.5f);
  const float f2 = fminf(fmaxf(f1 + fabsf(nf2[f] - f1) + MF, 0.f), 0.5f);
  const float f3 = fminf(fmaxf(fabsf(nf3[f]) + MF, 0.f), 0.5f);
  const float f4 = fminf(fmaxf(f3 + fabsf(nf4[f] - f3) + MF, 0.f), 0.5f);
  const float a1 = fabsf(amp1[f]);
  const float a2 = fabsf(amp2[f]);

  if (tid < FDIM) {
    const float t = (float)(tid + 1) / FS;
    {
      const float fcs = 0.5f * (f1 + f2) * FS, bws = (f2 - f1) * FS;
      const float pb = PIF * bws;
      ir1[tid] = a1 * expf(-2.f * pb * pb * (t * t)) * cosf(TPI * fcs * t);
    }
    {
      const float fcs = 0.5f * (f3 + f4) * FS, bws = (f4 - f3) * FS;
      const float pb = PIF * bws;
      ir2[tid] = a2 * expf(-2.f * pb * pb * (t * t)) * cosf(TPI * fcs * t);
    }
  }
  __syncthreads();
  norm_pm1_shared(ir1, scratch, tid);
  norm_pm1_shared(ir2, scratch, tid);

  if (tid < FDIM) {
    const int i = tid;
    const int plo = (i - 125 > 0) ? (i - 125) : 0;
    const int phi = (i + 125 < 250) ? (i + 125) : 250;
    float s = 0.f;
    for (int p = plo; p <= phi; ++p) s += ir1[p] * ir2[p + 125 - i];
    casc[i] = s;
  }
  __syncthreads();
  norm_pm1_shared(casc, scratch, tid);

  if (tid < KPAD) {
    float v = 0.f;
    if (tid < FDIM) {
      const float win = 0.54f - 0.46f * cosf(TPI * ((float)tid / 250.f));
      v = casc[tid] * win;
    }
    Wbf[(size_t)f * KPAD + tid] = f2bf(v);
  }
}

// ---------------------------------------------------------------------------
// Implicit-GEMM conv, round-16: MULTI-TASK BLOCKS (drain-hiding).
// r15 ablation measured: compute-only = 25.2 us, stores add +29 us ADDITIVE
// (writes drain at 5.6 TB/s but serialize with compute). Mechanism: waves
// s_waitcnt vmcnt(0) at s_endpgm -> block holds its slot until its stores
// drain -> slot throughput = compute + drain.
// Fix: block = one (t-chunk, batch); stage x ONCE; loop ft=0..4 over all 80
// filters (xs read-only across phases -> NO barriers in loop). ft-k stores
// drain under ft-k+1 compute; only ~1/5 of block store mass exposed at end.
// Staging work also drops 5x chip-wide. Grid 125x8 = 1000 blocks < 1024
// slots -> single generation, near-zero tail.
// Inner compute = r7 verbatim (validated orientation, 2-chain, addressing).
// #pragma unroll 1 on ft loop: one afr[8] set live (r6 spill lesson).
// ---------------------------------------------------------------------------
__global__ __launch_bounds__(256, 4) void conv_mfma_kernel(
    const float* __restrict__ xin, const unsigned short* __restrict__ Wbf,
    float* __restrict__ outp) {
  __shared__ __align__(16) unsigned int xs[XSTOT];
  const int tid = threadIdx.x;
  const int n0  = blockIdx.x * NCHUNK;
  const int b   = blockIdx.y;
  const int l   = tid & 63, w = tid >> 6;
  const int m   = l & 15, h = l >> 4;

  // ---- stage x ONCE as 8 shifted bf16-pair copies ----
  const float* xg = xin + (size_t)b * T_IN;
  for (int i = tid; i < CPYLEN - 4; i += 256) {
    float e[10];
    #pragma unroll
    for (int q = 0; q < 10; ++q) {
      const int g = n0 + 2 * i + q;
      e[q] = (g < T_IN) ? xg[g] : 0.f;
    }
    #pragma unroll
    for (int j = 0; j < 8; ++j)
      xs[j * CPYLEN + i] = packbf(e[j], e[j + 1]);
  }
  __syncthreads();   // only output-store-free point; vmcnt drain harmless here

  // lane-constant B(x) addressing (validated r4-r15):
  // tile at t_loc, chunk c -> copy m&7, 16B-unit index t_loc/8 + lane_q + 4c
  const unsigned int* psrc = xs + (m & 7) * CPYLEN;
  const int lane_q = h + (m >> 3);
  const int tw0 = w * 128;                     // wave's local t base (8 tiles)
  const short* Wp = (const short*)Wbf;

  #pragma unroll 1                             // keep ONE afr set live
  for (int ft = 0; ft < NFT; ++ft) {
    // W fragments (A-operand): lane row = m -> W[ft*16+m][k=8h+j+32c]
    bf16x8 afr[8];
    #pragma unroll
    for (int c = 0; c < 8; ++c)
      afr[c] = *(const bf16x8*)(Wp + (ft * 16 + m) * KPAD + c * 32 + h * 8);

    const size_t rowh = ((size_t)b * NFILT + ft * 16 + 4 * h) * T_OUT;

    for (int jp = 0; jp < 4; ++jp) {           // 4 pairs of 16-t tiles, 2 chains
      const int qA = ((tw0 + jp * 32) >> 3) + lane_q;
      f32x4 accA = (f32x4){0.f, 0.f, 0.f, 0.f};
      f32x4 accB = (f32x4){0.f, 0.f, 0.f, 0.f};

      #pragma unroll
      for (int c = 0; c < 8; ++c) {
        const bf16x8 xa = *(const bf16x8*)(psrc + 4 * (qA + 4 * c));
        const bf16x8 xb = *(const bf16x8*)(psrc + 4 * (qA + 2 + 4 * c));
        accA = __builtin_amdgcn_mfma_f32_16x16x32_bf16(afr[c], xa, accA, 0, 0, 0);
        accB = __builtin_amdgcn_mfma_f32_16x16x32_bf16(afr[c], xb, accB, 0, 0, 0);
      }

      const int tgA = n0 + tw0 + jp * 32 + m;  // D col = m
      const int tgB = tgA + 16;
      #pragma unroll
      for (int r = 0; r < 4; ++r) {            // D row = 4h + r
        const size_t rb = rowh + (size_t)r * T_OUT;
        if (tgA < T_OUT) outp[rb + tgA] = accA[r];
        if (tgB < T_OUT) outp[rb + tgB] = accB[r];
      }
    }
  }
}

// ---------------------------------------------------------------------------
extern "C" void kernel_launch(void* const* d_in, const int* in_sizes, int n_in,
                              void* d_out, int out_size, void* d_ws, size_t ws_size,
                              hipStream_t stream) {
  const float* x    = (const float*)d_in[0];
  const float* nf1  = (const float*)d_in[1];
  const float* nf2  = (const float*)d_in[2];
  const float* nf3  = (const float*)d_in[3];
  const float* nf4  = (const float*)d_in[4];
  const float* amp1 = (const float*)d_in[5];
  const float* amp2 = (const float*)d_in[6];
  unsigned short* Wbf = (unsigned short*)d_ws;   // 80*256*2 = 40 KB scratch
  float* out = (float*)d_out;

  build_filters_kernel<<<NFILT, 256, 0, stream>>>(nf1, nf2, nf3, nf4, amp1, amp2, Wbf);

  dim3 grid(NXB, 8);   // 125 x 8 = 1000 blocks; ft looped in-block
  conv_mfma_kernel<<<grid, 256, 0, stream>>>(x, Wbf, out);
}

// Round 17
// 58.887 us; speedup vs baseline: 1.4415x; 1.1725x over previous
//
#include <hip/hip_runtime.h>

#define FDIM   251
#define NFILT  80
#define KPAD   256        // K padded to 8 chunks of 32 (zeros past 250)
#define T_IN   64000
#define T_OUT  63750      // 64000 - 251 + 1
#define NCHUNK 512        // output positions per block; wave owns contiguous 128
#define NXB    125        // t-chunks
#define NFT    5          // filter tiles (16 filters each) - looped IN-block
#define CPYLEN 392        // dwords per shifted copy; 392 % 32 == 8 -> bank stagger
#define XSTOT  (8 * CPYLEN)   // 12.25 KB
#define WROW   129        // W LDS row stride (dwords): 128 + 1 -> <=4-way banks
#define WTOT   (NFILT * WROW) // 41.3 KB; total LDS 53.8 KB -> 3 blocks/CU

typedef short bf16x8 __attribute__((ext_vector_type(8)));
typedef float f32x4  __attribute__((ext_vector_type(4)));

__device__ __forceinline__ unsigned short f2bf(float f) {
  unsigned int u = __float_as_uint(f);
  unsigned int r = (u + 0x7fffu + ((u >> 16) & 1u)) >> 16;   // RNE
  return (unsigned short)r;
}
__device__ __forceinline__ unsigned int packbf(float a, float b) {
  return (unsigned int)f2bf(a) | ((unsigned int)f2bf(b) << 16);
}

// ---------------------------------------------------------------------------
// Filter construction (validated rounds 1-16). Emits bf16 W[80][256].
// ---------------------------------------------------------------------------
__device__ __forceinline__ void norm_pm1_shared(float* a, float* scratch, int tid) {
  float v  = (tid < FDIM) ? a[tid] : 0.f;
  float mn = (tid < FDIM) ? v : 1e30f;
  float mx = (tid < FDIM) ? v : -1e30f;
  #pragma unroll
  for (int o = 32; o > 0; o >>= 1) {
    mn = fminf(mn, __shfl_down(mn, o));
    mx = fmaxf(mx, __shfl_down(mx, o));
  }
  const int wid = tid >> 6;
  if ((tid & 63) == 0) { scratch[wid] = mn; scratch[4 + wid] = mx; }
  __syncthreads();
  if (tid == 0) {
    scratch[0] = fminf(fminf(scratch[0], scratch[1]), fminf(scratch[2], scratch[3]));
    scratch[4] = fmaxf(fmaxf(scratch[4], scratch[5]), fmaxf(scratch[6], scratch[7]));
  }
  __syncthreads();
  const float gmn = scratch[0], gmx = scratch[4];
  const float nv = 2.f * (v - gmn) / (gmx - gmn + 1e-6f) - 1.f;
  __syncthreads();
  float s = (tid < FDIM) ? nv : 0.f;
  #pragma unroll
  for (int o = 32; o > 0; o >>= 1) s += __shfl_down(s, o);
  if ((tid & 63) == 0) scratch[wid] = s;
  __syncthreads();
  if (tid == 0) scratch[0] = (scratch[0] + scratch[1] + scratch[2] + scratch[3]) / 251.f;
  __syncthreads();
  const float mean = scratch[0];
  if (tid < FDIM) a[tid] = nv - mean;
  __syncthreads();
}

__global__ __launch_bounds__(256) void build_filters_kernel(
    const float* __restrict__ nf1, const float* __restrict__ nf2,
    const float* __restrict__ nf3, const float* __restrict__ nf4,
    const float* __restrict__ amp1, const float* __restrict__ amp2,
    unsigned short* __restrict__ Wbf) {
  __shared__ float ir1[FDIM], ir2[FDIM], casc[FDIM];
  __shared__ float scratch[8];
  const int f = blockIdx.x, tid = threadIdx.x;
  const float FS  = 16000.f;
  const float MF  = 50.f / 16000.f;
  const float PIF = 3.14159265358979323846f;
  const float TPI = 6.28318530717958647692f;

  const float f1 = fminf(fmaxf(fabsf(nf1[f]) + MF, 0.f), 0.5f);
  const float f2 = fminf(fmaxf(f1 + fabsf(nf2[f] - f1) + MF, 0.f), 0.5f);
  const float f3 = fminf(fmaxf(fabsf(nf3[f]) + MF, 0.f), 0.5f);
  const float f4 = fminf(fmaxf(f3 + fabsf(nf4[f] - f3) + MF, 0.f), 0.5f);
  const float a1 = fabsf(amp1[f]);
  const float a2 = fabsf(amp2[f]);

  if (tid < FDIM) {
    const float t = (float)(tid + 1) / FS;
    {
      const float fcs = 0.5f * (f1 + f2) * FS, bws = (f2 - f1) * FS;
      const float pb = PIF * bws;
      ir1[tid] = a1 * expf(-2.f * pb * pb * (t * t)) * cosf(TPI * fcs * t);
    }
    {
      const float fcs = 0.5f * (f3 + f4) * FS, bws = (f4 - f3) * FS;
      const float pb = PIF * bws;
      ir2[tid] = a2 * expf(-2.f * pb * pb * (t * t)) * cosf(TPI * fcs * t);
    }
  }
  __syncthreads();
  norm_pm1_shared(ir1, scratch, tid);
  norm_pm1_shared(ir2, scratch, tid);

  if (tid < FDIM) {
    const int i = tid;
    const int plo = (i - 125 > 0) ? (i - 125) : 0;
    const int phi = (i + 125 < 250) ? (i + 125) : 250;
    float s = 0.f;
    for (int p = plo; p <= phi; ++p) s += ir1[p] * ir2[p + 125 - i];
    casc[i] = s;
  }
  __syncthreads();
  norm_pm1_shared(casc, scratch, tid);

  if (tid < KPAD) {
    float v = 0.f;
    if (tid < FDIM) {
      const float win = 0.54f - 0.46f * cosf(TPI * ((float)tid / 250.f));
      v = casc[tid] * win;
    }
    Wbf[(size_t)f * KPAD + tid] = f2bf(v);
  }
}

// ---------------------------------------------------------------------------
// Implicit-GEMM conv, round-17: multi-task block with ZERO post-store vmem
// waits. Diagnosis chain: r15 ablation -> conv = compute(25) + stores(29)
// ADDITIVE; r16 regression -> global afr reloads between phases force
// vmcnt waits that drain older stores (vmcnt counts loads AND stores,
// in order). Generalized: any global READ after stores serializes against
// the chip-wide write backlog; in r7 that read is each block's x staging.
// Fix: stage x AND all of W into LDS up front (single global-read phase,
// before any store), then run 5 ft phases with afr from LDS (lgkmcnt,
// independent of store counter). After the first store, the instruction
// stream contains no vmem wait until endpgm -> stores pipeline freely
// under compute; exposed drain = last phase only (~1/5).
// LDS: xs 12.25 KB + W 41.3 KB (row stride 129 -> <=4-way banks on afr
// b32 reads, 160 reads/block-wave = negligible) = 53.8 KB -> 3 blocks/CU.
// launch_bounds(256,3) -> 168 VGPR cap, no spill risk (r6 lesson).
// Inner compute = r7 verbatim; same products, same order -> absmax 0.125.
// ---------------------------------------------------------------------------
__global__ __launch_bounds__(256, 3) void conv_mfma_kernel(
    const float* __restrict__ xin, const unsigned short* __restrict__ Wbf,
    float* __restrict__ outp) {
  __shared__ __align__(16) unsigned int xs[XSTOT];
  __shared__ __align__(16) unsigned int wlds[WTOT];
  const int tid = threadIdx.x;
  const int n0  = blockIdx.x * NCHUNK;
  const int b   = blockIdx.y;
  const int l   = tid & 63, w = tid >> 6;
  const int m   = l & 15, h = l >> 4;

  // ---- stage x ONCE as 8 shifted bf16-pair copies ----
  const float* xg = xin + (size_t)b * T_IN;
  for (int i = tid; i < CPYLEN - 4; i += 256) {
    float e[10];
    #pragma unroll
    for (int q = 0; q < 10; ++q) {
      const int g = n0 + 2 * i + q;
      e[q] = (g < T_IN) ? xg[g] : 0.f;
    }
    #pragma unroll
    for (int j = 0; j < 8; ++j)
      xs[j * CPYLEN + i] = packbf(e[j], e[j + 1]);
  }

  // ---- stage ALL of W into LDS (row stride 129 dwords) ----
  {
    const unsigned int* Wg = (const unsigned int*)Wbf;   // [80][128] dwords
    for (int idx = tid; idx < NFILT * 128; idx += 256) {
      const int f = idx >> 7, d = idx & 127;
      wlds[f * WROW + d] = Wg[f * 128 + d];
    }
  }
  __syncthreads();   // the ONLY barrier; before any output store

  // lane-constant B(x) addressing (validated r4-r16):
  // tile at t_loc, chunk c -> copy m&7, 16B-unit index t_loc/8 + lane_q + 4c
  const unsigned int* psrc = xs + (m & 7) * CPYLEN;
  const int lane_q = h + (m >> 3);
  const int tw0 = w * 128;                     // wave's local t base (8 tiles)

  #pragma unroll 1                             // one afr set live (r6 lesson)
  for (int ft = 0; ft < NFT; ++ft) {
    // W fragments from LDS: dword idx = (ft*16+m)*129 + c*16 + h*4 + q
    const unsigned int* wrow = wlds + (ft * 16 + m) * WROW + h * 4;
    bf16x8 afr[8];
    #pragma unroll
    for (int c = 0; c < 8; ++c) {
      union { unsigned int u[4]; bf16x8 v; } t;
      t.u[0] = wrow[c * 16 + 0];
      t.u[1] = wrow[c * 16 + 1];
      t.u[2] = wrow[c * 16 + 2];
      t.u[3] = wrow[c * 16 + 3];
      afr[c] = t.v;
    }

    const size_t rowh = ((size_t)b * NFILT + ft * 16 + 4 * h) * T_OUT;

    for (int jp = 0; jp < 4; ++jp) {           // 4 pairs of 16-t tiles, 2 chains
      const int qA = ((tw0 + jp * 32) >> 3) + lane_q;
      f32x4 accA = (f32x4){0.f, 0.f, 0.f, 0.f};
      f32x4 accB = (f32x4){0.f, 0.f, 0.f, 0.f};

      #pragma unroll
      for (int c = 0; c < 8; ++c) {
        const bf16x8 xa = *(const bf16x8*)(psrc + 4 * (qA + 4 * c));
        const bf16x8 xb = *(const bf16x8*)(psrc + 4 * (qA + 2 + 4 * c));
        accA = __builtin_amdgcn_mfma_f32_16x16x32_bf16(afr[c], xa, accA, 0, 0, 0);
        accB = __builtin_amdgcn_mfma_f32_16x16x32_bf16(afr[c], xb, accB, 0, 0, 0);
      }

      const int tgA = n0 + tw0 + jp * 32 + m;  // D col = m
      const int tgB = tgA + 16;
      #pragma unroll
      for (int r = 0; r < 4; ++r) {            // D row = 4h + r
        const size_t rb = rowh + (size_t)r * T_OUT;
        if (tgA < T_OUT) outp[rb + tgA] = accA[r];
        if (tgB < T_OUT) outp[rb + tgB] = accB[r];
      }
    }
  }
}

// ---------------------------------------------------------------------------
extern "C" void kernel_launch(void* const* d_in, const int* in_sizes, int n_in,
                              void* d_out, int out_size, void* d_ws, size_t ws_size,
                              hipStream_t stream) {
  const float* x    = (const float*)d_in[0];
  const float* nf1  = (const float*)d_in[1];
  const float* nf2  = (const float*)d_in[2];
  const float* nf3  = (const float*)d_in[3];
  const float* nf4  = (const float*)d_in[4];
  const float* amp1 = (const float*)d_in[5];
  const float* amp2 = (const float*)d_in[6];
  unsigned short* Wbf = (unsigned short*)d_ws;   // 80*256*2 = 40 KB scratch
  float* out = (float*)d_out;

  build_filters_kernel<<<NFILT, 256, 0, stream>>>(nf1, nf2, nf3, nf4, amp1, amp2, Wbf);

  dim3 grid(NXB, 8);   // 125 x 8 = 1000 blocks; ft looped in-block
  conv_mfma_kernel<<<grid, 256, 0, stream>>>(x, Wbf, out);
}